// Round 7
// baseline (1168.251 us; speedup 1.0000x reference)
//
#include <hip/hip_runtime.h>
#include <hip/hip_bf16.h>

#define DIM   1024
#define NTOK  8192

using bf16 = __hip_bfloat16;
typedef __attribute__((ext_vector_type(8))) short bf16x8;
typedef __attribute__((ext_vector_type(4))) float f32x4;

__device__ __forceinline__ unsigned short f2b(float x) {
  union { __hip_bfloat16 h; unsigned short u; } cv;
  cv.h = __float2bfloat16(x);
  return cv.u;
}
__device__ __forceinline__ float b2f(short s) {
  unsigned u = ((unsigned)(unsigned short)s) << 16;
  float f; __builtin_memcpy(&f, &u, 4); return f;
}

// ---------------- cast f32 -> bf16 ----------------
__global__ __launch_bounds__(256) void cast_f32_bf16(const float* __restrict__ in,
                                                     bf16* __restrict__ out, int n4) {
  int i = blockIdx.x * 256 + threadIdx.x;
  if (i < n4) {
    const float4 v = ((const float4*)in)[i];
    ushort4 p;
    p.x = f2b(v.x); p.y = f2b(v.y); p.z = f2b(v.z); p.w = f2b(v.w);
    ((ushort4*)out)[i] = p;
  }
}

// ------------- tiled transpose + cast: in[R][C] f32 -> out[C][R] bf16 -------------
__global__ __launch_bounds__(256) void transpose_cast32(const float* __restrict__ in,
                                                        bf16* __restrict__ out, int R, int C) {
  __shared__ float t[32][33];
  const int tilesC = C / 32;
  const int c0 = (blockIdx.x % tilesC) * 32;
  const int r0 = (blockIdx.x / tilesC) * 32;
  const int tx = threadIdx.x & 31, ty = threadIdx.x >> 5;
  #pragma unroll
  for (int i = 0; i < 4; ++i) {
    int r = ty + i * 8;
    t[r][tx] = in[(size_t)(r0 + r) * C + c0 + tx];
  }
  __syncthreads();
  #pragma unroll
  for (int i = 0; i < 4; ++i) {
    int cr = ty + i * 8;
    out[(size_t)(c0 + cr) * R + r0 + tx] = __float2bfloat16(t[tx][cr]);
  }
}

// ------------- bf16 transpose, 64x64 tiles, vectorized both sides, dual-input -------------
__global__ __launch_bounds__(256) void transpose_bf16(const short* __restrict__ in,
                                                      short* __restrict__ out,
                                                      const short* __restrict__ in2,
                                                      short* __restrict__ out2,
                                                      int R, int C) {
  __shared__ short t[64][72];
  const int tilesC = C >> 6;
  const int tilesPer = (R >> 6) * tilesC;
  int bid = blockIdx.x;
  const short* src = in; short* dst = out;
  if (bid >= tilesPer) { bid -= tilesPer; src = in2; dst = out2; }
  const int r0 = (bid / tilesC) << 6, c0 = (bid % tilesC) << 6;
  const int tr = threadIdx.x >> 3, tc8 = (threadIdx.x & 7) << 3;
  #pragma unroll
  for (int p = 0; p < 2; ++p) {
    int r = tr + p * 32;
    int sc = tc8 ^ (((r >> 3) & 7) << 3);
    *(bf16x8*)&t[r][sc] = *(const bf16x8*)&src[(size_t)(r0 + r) * C + c0 + tc8];
  }
  __syncthreads();
  #pragma unroll
  for (int p = 0; p < 2; ++p) {
    int oc = tr + p * 32;
    bf16x8 v;
    #pragma unroll
    for (int e = 0; e < 8; ++e) {
      int a = tc8 + e;
      v[e] = t[a][oc ^ (((a >> 3) & 7) << 3)];
    }
    *(bf16x8*)&dst[(size_t)(c0 + oc) * R + r0 + tc8] = v;
  }
}

// ---------------- pack 6 bias vectors ----------------
__global__ __launch_bounds__(256) void pack_bias(const float* b0, const float* b1,
                                                 const float* b2, const float* b3,
                                                 const float* b4, const float* b5,
                                                 float* __restrict__ out) {
  int i = blockIdx.x * 256 + threadIdx.x;
  if (i < 6 * DIM) {
    int s = i >> 10, o = i & 1023;
    const float* p = (s == 0) ? b0 : (s == 1) ? b1 : (s == 2) ? b2 : (s == 3) ? b3 : (s == 4) ? b4 : b5;
    out[i] = p[o];
  }
}

// ============ 128x128 NT GEMM, BK=32, triple-buffered, 3 blocks/CU ============
// C[M,N] = A[M,K] @ Bt[N,K]^T. 256 thr = 4 waves (2x2), wave tile 64x64.
// LDS: A 3x8KB + B 3x8KB = 48 KB -> 3 blocks/CU. Both-sides chunk swizzle:
// phys chunk p of row r holds logical chunk p ^ ((r>>1)&3).
// EPI: 2 = sigmoid->f32 | 3 = f32 ctx + IN-LOOP f32 probs expansion from staged
//      bf16 A-tiles (block's n-tile j expands k-slice [j*1024,(j+1)*1024)) |
//      4 = sigmoid->bf16 ONLY (f32 probs produced by EPI=3's expansion) |
//      5 = fused QKV proj
template<int EPI, bool DUAL>
__global__ __launch_bounds__(256, 3) void gemm128(
    const bf16* __restrict__ A,  const bf16* __restrict__ Bt,
    const bf16* __restrict__ A2, const bf16* __restrict__ Bt2,
    int M, int N, int K, int TM, int perDir,
    const float* __restrict__ bias, const float* __restrict__ bias2, float scale,
    float* __restrict__ Cf, float* __restrict__ Cf2,
    bf16* __restrict__ Cb, bf16* __restrict__ Cb2,
    float* __restrict__ Pf, float* __restrict__ Pf2,
    bf16* __restrict__ Cq, bf16* __restrict__ Ck, bf16* __restrict__ Cv,
    bf16* __restrict__ Cq2, bf16* __restrict__ Ck2, bf16* __restrict__ Cv2)
{
  __shared__ __align__(16) char smem[49152];
  bf16* sA = (bf16*)smem;               // 3 slots x 4096 elems (128x32)
  bf16* sB = (bf16*)(smem + 24576);     // 3 slots x 4096 elems
  float* Lf = (float*)smem;             // epilogue: 64 x 128 f32 (32 KB)

  const int t    = threadIdx.x;
  const int lane = t & 63, wid = t >> 6;
  const int wr = wid >> 1, wc = wid & 1;
  const int lr = lane & 15, kg = lane >> 4;

  // XCD-aware bijective swizzle (all grids are multiples of 8)
  const int nwg = gridDim.x;
  int bid = blockIdx.x;
  { const int q = nwg >> 3; bid = (bid & 7) * q + (bid >> 3); }

  const bf16* Au = A; const bf16* BtU = Bt;
  float* CfU = Cf; bf16* CbU = Cb; float* PfU = Pf;
  if (DUAL && bid >= perDir) { bid -= perDir; Au = A2; BtU = Bt2; CfU = Cf2; CbU = Cb2; PfU = Pf2; }

  // stripe mapping: 8 consecutive bids share one A-panel (bm), sweep 8 bn
  const int gw = TM << 3;
  const int s  = bid / gw, w = bid % gw;
  const int bm = (w >> 3) << 7;
  const int bn = ((s << 3) + (w & 7)) << 7;
  const int nj = bn >> 7;   // PV: n-tile index (0..7) -> k-slice owner

  // proj: dual-by-row select
  const float* biasU = bias;
  bf16 *CqU = Cq, *CkU = Ck, *CvU = Cv;
  int bmL = bm;
  if (EPI == 5 && bm >= (M >> 1)) {
    BtU = Bt2; biasU = bias2; CqU = Cq2; CkU = Ck2; CvU = Cv2; bmL = bm - (M >> 1);
  }

  // staging: thread t writes LDS phys chunk (t&3) of row (t>>2); global source
  // column pre-swizzled so phys chunk p of row r = logical chunk p^((r>>1)&3).
  const int srow = t >> 2;
  const int scol = ((t & 3) ^ ((t >> 3) & 3)) * 8;
  const size_t gA = (size_t)(bm + srow) * K + scol;
  const size_t gB = (size_t)(bn + srow) * K + scol;

#define STAGE(slot, isB, R0, tt_) \
  __builtin_amdgcn_global_load_lds( \
    (const __attribute__((address_space(1))) unsigned int*)(((isB) ? BtU + gB : Au + gA) + (size_t)(R0) * K + (size_t)(tt_) * 32), \
    (__attribute__((address_space(3))) unsigned int*)(((isB) ? sB : sA) + (slot) * 4096 + (R0) * 32 + t * 8), \
    16, 0, 0)

  // fragment reads: phys chunk = kg ^ ((lr>>1)&3)
  const int swz  = (kg ^ ((lr >> 1) & 3)) * 8;
  const int aoff = (wr * 64 + lr) * 32 + swz;
  const int boff = (wc * 64 + lr) * 32 + swz;

  f32x4 acc[4][4] = {};
  const int NT = K >> 5;

  // prologue: tiles 0,1 -> slots 0,1; wait tile0
  STAGE(0, 0, 0, 0); STAGE(0, 0, 64, 0); STAGE(0, 1, 0, 0); STAGE(0, 1, 64, 0);
  STAGE(1, 0, 0, 1); STAGE(1, 0, 64, 1); STAGE(1, 1, 0, 1); STAGE(1, 1, 64, 1);
  asm volatile("s_waitcnt vmcnt(4)" ::: "memory");
  __builtin_amdgcn_sched_barrier(0);
  __builtin_amdgcn_s_barrier();

  int cur = 0, stg = 2;
  for (int tt = 0; tt < NT; ++tt) {
    bf16x8 a[4], b[4];
    const bf16* pa = sA + cur * 4096 + aoff;
    const bf16* pb = sB + cur * 4096 + boff;
    #pragma unroll
    for (int i = 0; i < 4; ++i) a[i] = *(const bf16x8*)(pa + i * 512);
    #pragma unroll
    for (int i = 0; i < 4; ++i) b[i] = *(const bf16x8*)(pb + i * 512);
    if (tt + 2 < NT) {
      STAGE(stg, 0, 0, tt + 2); STAGE(stg, 0, 64, tt + 2);
      STAGE(stg, 1, 0, tt + 2); STAGE(stg, 1, 64, tt + 2);
    }
    __builtin_amdgcn_s_barrier();
    asm volatile("s_waitcnt lgkmcnt(0)" ::: "memory");
    __builtin_amdgcn_sched_barrier(0);
    __builtin_amdgcn_s_setprio(1);
    #pragma unroll
    for (int mi = 0; mi < 4; ++mi)
      #pragma unroll
      for (int n = 0; n < 4; ++n)
        acc[mi][n] = __builtin_amdgcn_mfma_f32_16x16x32_bf16(a[mi], b[n], acc[mi][n], 0, 0, 0);
    __builtin_amdgcn_s_setprio(0);

    // ---- PV only: expand this block's k-slice of staged bf16 probs to f32 ----
    if (EPI == 3 && (tt >> 5) == nj) {
      const int r  = t >> 1;              // 0..127
      const int pc = (t & 1) * 2;         // phys chunks {0,1} or {2,3}
      const int xr = (r >> 1) & 3;
      const bf16* src = sA + cur * 4096 + r * 32 + pc * 8;
      float* dst = PfU + (size_t)(bm + r) * NTOK + tt * 32;
      #pragma unroll
      for (int c = 0; c < 2; ++c) {
        bf16x8 v = *(const bf16x8*)(src + c * 8);
        const int lcol = ((pc + c) ^ xr) * 8;
        f32x4 lo, hi;
        #pragma unroll
        for (int e = 0; e < 4; ++e) { lo[e] = b2f(v[e]); hi[e] = b2f(v[4 + e]); }
        __builtin_nontemporal_store(lo, (f32x4*)&dst[lcol]);
        __builtin_nontemporal_store(hi, (f32x4*)&dst[lcol + 4]);
      }
    }

    if (tt + 2 < NT) { asm volatile("s_waitcnt vmcnt(4)" ::: "memory"); }
    else             { asm volatile("s_waitcnt vmcnt(0)" ::: "memory"); }
    __builtin_amdgcn_sched_barrier(0);
    __builtin_amdgcn_s_barrier();
    cur = (cur == 2) ? 0 : cur + 1;
    stg = (stg == 2) ? 0 : stg + 1;
  }
#undef STAGE

  // ======== LDS-transposed epilogue (64-row chunks), coalesced stores ========
  float bv[4];
  if (EPI == 5) {
    #pragma unroll
    for (int n = 0; n < 4; ++n) bv[n] = biasU[bn + wc * 64 + n * 16 + lr];
  }

  #pragma unroll
  for (int h = 0; h < 2; ++h) {
    if (wr == h) {
      #pragma unroll
      for (int mi = 0; mi < 4; ++mi)
        #pragma unroll
        for (int n = 0; n < 4; ++n)
          #pragma unroll
          for (int e = 0; e < 4; ++e) {
            const int lrow = mi * 16 + kg * 4 + e;          // 0..63
            const int lcol = wc * 64 + n * 16 + lr;         // 0..127
            float v = acc[mi][n][e];
            if (EPI == 2 || EPI == 4) v = 1.0f / (1.0f + __expf(-v * scale));
            if (EPI == 5) v += bv[n];
            Lf[lrow * 128 + lcol] = v;
          }
    }
    __syncthreads();
    #pragma unroll
    for (int rr = 0; rr < 8; ++rr) {
      const int lrow = wid * 16 + rr * 2 + (lane >> 5);
      const int col  = (lane & 31) * 4;
      const f32x4 v = *(const f32x4*)&Lf[lrow * 128 + col];
      const int gr = bm + h * 64 + lrow;
      if (EPI == 2) {
        __builtin_nontemporal_store(v, (f32x4*)&CfU[(size_t)gr * N + bn + col]);
      } else if (EPI == 4) {
        ushort4 p; p.x = f2b(v[0]); p.y = f2b(v[1]); p.z = f2b(v[2]); p.w = f2b(v[3]);
        *(ushort4*)&CbU[(size_t)gr * N + bn + col] = p;
      } else if (EPI == 3) {
        __builtin_nontemporal_store(v, (f32x4*)&CfU[(size_t)gr * N + bn + col]);
      } else if (EPI == 5) {
        const int seg = bn >> 10;
        const int cl  = (bn & 1023) + col;
        const int r   = bmL + h * 64 + lrow;
        bf16* sel = (seg == 0) ? CqU : (seg == 1) ? CkU : CvU;
        ushort4 p; p.x = f2b(v[0]); p.y = f2b(v[1]); p.z = f2b(v[2]); p.w = f2b(v[3]);
        *(ushort4*)&sel[(size_t)r * DIM + cl] = p;
      }
    }
    __syncthreads();
  }
}

// ================= legacy 128x128 GEMM (low-ws fallback only) =================
template<int EPI, bool A_F32>
__global__ __launch_bounds__(256) void gemm_nt(
    const void* __restrict__ Ap, const bf16* __restrict__ Bt,
    int M, int N, int K,
    float scale, float* __restrict__ Cf)
{
  __shared__ bf16 As[128 * 32];
  __shared__ bf16 Bs[128 * 32];
  const int tid  = threadIdx.x;
  const int lane = tid & 63, wid = tid >> 6;
  const int wrr = wid >> 1, wcc = wid & 1;
  const int tilesN = N >> 7;
  const int nwg = gridDim.x;
  int bid = blockIdx.x;
  if ((nwg & 7) == 0) { const int q = nwg >> 3; bid = (bid & 7) * q + (bid >> 3); }
  const int bm = (bid / tilesN) * 128, bn = (bid % tilesN) * 128;
  f32x4 acc[4][4] = {};
  const bf16*  Ab16 = (const bf16*)Ap;
  const float* Af32 = (const float*)Ap;
  const int srow = tid >> 2, sc8 = (tid & 3) * 8;
  const int frow = tid >> 3, fc4 = (tid & 7) * 4;

  for (int k0 = 0; k0 < K; k0 += 32) {
    if (A_F32) {
      #pragma unroll
      for (int is = 0; is < 4; ++is) {
        int row = is * 32 + frow;
        const float4 v = *(const float4*)(Af32 + (size_t)(bm + row) * K + k0 + fc4);
        ushort4 p; p.x = f2b(v.x); p.y = f2b(v.y); p.z = f2b(v.z); p.w = f2b(v.w);
        *(ushort4*)(&As[row * 32 + fc4]) = p;
      }
    } else {
      #pragma unroll
      for (int is = 0; is < 2; ++is) {
        int row = is * 64 + srow;
        const bf16* g = Ab16 + (size_t)(bm + row) * K + k0 + sc8;
        __builtin_amdgcn_global_load_lds(
            (const __attribute__((address_space(1))) unsigned int*)g,
            (__attribute__((address_space(3))) unsigned int*)(&As[row * 32 + sc8]), 16, 0, 0);
      }
    }
    #pragma unroll
    for (int is = 0; is < 2; ++is) {
      int row = is * 64 + srow;
      const bf16* g = Bt + (size_t)(bn + row) * K + k0 + sc8;
      __builtin_amdgcn_global_load_lds(
          (const __attribute__((address_space(1))) unsigned int*)g,
          (__attribute__((address_space(3))) unsigned int*)(&Bs[row * 32 + sc8]), 16, 0, 0);
    }
    __syncthreads();
    const int lrr = lane & 15, kgg = lane >> 4;
    bf16x8 af[4], bfv[4];
    #pragma unroll
    for (int i = 0; i < 4; ++i)
      af[i] = *(const bf16x8*)(&As[(wrr * 64 + i * 16 + lrr) * 32 + kgg * 8]);
    #pragma unroll
    for (int j = 0; j < 4; ++j)
      bfv[j] = *(const bf16x8*)(&Bs[(wcc * 64 + j * 16 + lrr) * 32 + kgg * 8]);
    #pragma unroll
    for (int i = 0; i < 4; ++i)
      #pragma unroll
      for (int j = 0; j < 4; ++j)
        acc[i][j] = __builtin_amdgcn_mfma_f32_16x16x32_bf16(af[i], bfv[j], acc[i][j], 0, 0, 0);
    __syncthreads();
  }
  const int r0 = bm + wrr * 64 + (lane >> 4) * 4;
  const int c0 = bn + wcc * 64 + (lane & 15);
  if (EPI == 2) {
    #pragma unroll
    for (int i = 0; i < 4; ++i)
      #pragma unroll
      for (int j = 0; j < 4; ++j)
        #pragma unroll
        for (int e = 0; e < 4; ++e) {
          float pr = 1.0f / (1.0f + __expf(-acc[i][j][e] * scale));
          Cf[(size_t)(r0 + i * 16 + e) * N + c0 + j * 16] = pr;
        }
  } else {
    #pragma unroll
    for (int i = 0; i < 4; ++i)
      #pragma unroll
      for (int j = 0; j < 4; ++j)
        #pragma unroll
        for (int e = 0; e < 4; ++e)
          Cf[(size_t)(r0 + i * 16 + e) * N + c0 + j * 16] = acc[i][j][e];
  }
}

extern "C" void kernel_launch(void* const* d_in, const int* in_sizes, int n_in,
                              void* d_out, int out_size, void* d_ws, size_t ws_size,
                              hipStream_t stream) {
  const float* x1 = (const float*)d_in[0];
  const float* x2 = (const float*)d_in[1];
  const float* W[6] = { (const float*)d_in[2],  (const float*)d_in[4],  (const float*)d_in[6],
                        (const float*)d_in[8],  (const float*)d_in[10], (const float*)d_in[12] };
  const float* B[6] = { (const float*)d_in[3],  (const float*)d_in[5],  (const float*)d_in[7],
                        (const float*)d_in[9],  (const float*)d_in[11], (const float*)d_in[13] };

  const size_t MD = (size_t)NTOK * DIM;
  const size_t DD = (size_t)DIM * DIM;
  const size_t NN = (size_t)NTOK * NTOK;

  bf16* ws   = (bf16*)d_ws;
  bf16* x1b  = ws;                         // contiguous with x2b -> proj A (16384 rows)
  bf16* x2b  = x1b + MD;
  bf16* wt1  = x2b + MD;
  bf16* wt2  = wt1 + 3 * DD;
  float* bstack = (float*)(wt2 + 3 * DD);  // 6144 f32 in 16384-bf16 slot
  bf16* q1   = wt2 + 3 * DD + 16384;
  bf16* k1   = q1 + MD;
  bf16* q2   = k1 + MD;
  bf16* k2   = q2 + MD;
  bf16* v1r  = k2 + MD;
  bf16* v2r  = v1r + MD;
  bf16* v1T  = v2r + MD;
  bf16* v2T  = v1T + MD;
  bf16* probsb = v2T + MD;                 // 2 x 64M bf16

  const size_t topBytes = ((size_t)(10 * MD + 6 * DD + 16384) + 2 * NN) * 2;
  const bool top = (ws_size >= topBytes);  // ~440 MB; measured ws ≈ 2.4 GB

  float* out    = (float*)d_out;
  float* ctx2   = out;
  float* probs2 = ctx2 + MD;
  float* ctx1   = probs2 + NN;
  float* probs1 = ctx1 + MD;

  const float scale = 1.0f / 32.0f;

  {
    int n4 = (int)(MD / 4);
    int blks = (n4 + 255) / 256;
    cast_f32_bf16<<<blks, 256, 0, stream>>>(x1, x1b, n4);
    cast_f32_bf16<<<blks, 256, 0, stream>>>(x2, x2b, n4);
  }
  {
    int blks = (DIM / 32) * (DIM / 32);
    transpose_cast32<<<blks, 256, 0, stream>>>(W[0], wt1 + 0 * DD, DIM, DIM);
    transpose_cast32<<<blks, 256, 0, stream>>>(W[1], wt1 + 1 * DD, DIM, DIM);
    transpose_cast32<<<blks, 256, 0, stream>>>(W[2], wt1 + 2 * DD, DIM, DIM);
    transpose_cast32<<<blks, 256, 0, stream>>>(W[3], wt2 + 0 * DD, DIM, DIM);
    transpose_cast32<<<blks, 256, 0, stream>>>(W[4], wt2 + 1 * DD, DIM, DIM);
    transpose_cast32<<<blks, 256, 0, stream>>>(W[5], wt2 + 2 * DD, DIM, DIM);
  }
  pack_bias<<<24, 256, 0, stream>>>(B[0], B[1], B[2], B[3], B[4], B[5], bstack);

  // fused QKV projection: A = [x1b;x2b] (16384 x 1024), N = 3072. grid 3072.
  gemm128<5, false><<<128 * 24, 256, 0, stream>>>(
      x1b, wt1, nullptr, wt2, 2 * NTOK, 3 * DIM, DIM, 128, 3072,
      bstack, bstack + 3 * DIM, 0.f,
      nullptr, nullptr, nullptr, nullptr, nullptr, nullptr,
      q1, k1, v1r, q2, k2, v2r);

  // v transpose: [8192,1024] -> [1024,8192], both inputs
  transpose_bf16<<<2 * (NTOK / 64) * (DIM / 64), 256, 0, stream>>>(
      (const short*)v1r, (short*)v1T, (const short*)v2r, (short*)v2T, NTOK, DIM);

  const int perQK = (NTOK / 128) * (NTOK / 128);  // 4096
  const int perPV = (NTOK / 128) * (DIM / 128);   // 512

  if (top) {
    // fused dual QK: bf16 probs ONLY (f32 probs produced by PV's in-loop expand)
    gemm128<4, true><<<2 * perQK, 256, 0, stream>>>(
        q1, k2, q2, k1, NTOK, NTOK, DIM, 64, perQK,
        nullptr, nullptr, scale,
        nullptr, nullptr, probsb, probsb + NN, nullptr, nullptr,
        nullptr, nullptr, nullptr, nullptr, nullptr, nullptr);
    // fused dual PV: ctx2 = probsb@v2, ctx1 = probsb'@v1 (K = 8192)
    // + expands staged bf16 probs tiles to f32 probs2/probs1
    gemm128<3, true><<<2 * perPV, 256, 0, stream>>>(
        probsb, v2T, probsb + NN, v1T, NTOK, DIM, NTOK, 64, perPV,
        nullptr, nullptr, 0.f,
        ctx2, ctx1, nullptr, nullptr, probs2, probs1,
        nullptr, nullptr, nullptr, nullptr, nullptr, nullptr);
  } else {
    // fallback: f32 probs from QK; PV re-reads f32 probs with convert-on-stage
    gemm128<2, false><<<perQK, 256, 0, stream>>>(
        q1, k2, nullptr, nullptr, NTOK, NTOK, DIM, 64, perQK,
        nullptr, nullptr, scale,
        probs2, nullptr, nullptr, nullptr, nullptr, nullptr,
        nullptr, nullptr, nullptr, nullptr, nullptr, nullptr);
    gemm_nt<3, true><<<(NTOK / 128) * (DIM / 128), 256, 0, stream>>>(
        probs2, v2T, NTOK, DIM, NTOK, 0.f, ctx2);
    gemm128<2, false><<<perQK, 256, 0, stream>>>(
        q2, k1, nullptr, nullptr, NTOK, NTOK, DIM, 64, perQK,
        nullptr, nullptr, scale,
        probs1, nullptr, nullptr, nullptr, nullptr, nullptr,
        nullptr, nullptr, nullptr, nullptr, nullptr, nullptr);
    gemm_nt<3, true><<<(NTOK / 128) * (DIM / 128), 256, 0, stream>>>(
        probs1, v1T, NTOK, DIM, NTOK, 0.f, ctx1);
  }
}

// Round 8
// 893.575 us; speedup vs baseline: 1.3074x; 1.3074x over previous
//
#include <hip/hip_runtime.h>
#include <hip/hip_bf16.h>

#define DIM   1024
#define NTOK  8192

using bf16 = __hip_bfloat16;
typedef __attribute__((ext_vector_type(8))) short bf16x8;
typedef __attribute__((ext_vector_type(4))) float f32x4;

__device__ __forceinline__ unsigned short f2b(float x) {
  union { __hip_bfloat16 h; unsigned short u; } cv;
  cv.h = __float2bfloat16(x);
  return cv.u;
}

// ---------------- cast f32 -> bf16 ----------------
__global__ __launch_bounds__(256) void cast_f32_bf16(const float* __restrict__ in,
                                                     bf16* __restrict__ out, int n4) {
  int i = blockIdx.x * 256 + threadIdx.x;
  if (i < n4) {
    const float4 v = ((const float4*)in)[i];
    ushort4 p;
    p.x = f2b(v.x); p.y = f2b(v.y); p.z = f2b(v.z); p.w = f2b(v.w);
    ((ushort4*)out)[i] = p;
  }
}

// ------------- tiled transpose + cast: in[R][C] f32 -> out[C][R] bf16 -------------
__global__ __launch_bounds__(256) void transpose_cast32(const float* __restrict__ in,
                                                        bf16* __restrict__ out, int R, int C) {
  __shared__ float t[32][33];
  const int tilesC = C / 32;
  const int c0 = (blockIdx.x % tilesC) * 32;
  const int r0 = (blockIdx.x / tilesC) * 32;
  const int tx = threadIdx.x & 31, ty = threadIdx.x >> 5;
  #pragma unroll
  for (int i = 0; i < 4; ++i) {
    int r = ty + i * 8;
    t[r][tx] = in[(size_t)(r0 + r) * C + c0 + tx];
  }
  __syncthreads();
  #pragma unroll
  for (int i = 0; i < 4; ++i) {
    int cr = ty + i * 8;
    out[(size_t)(c0 + cr) * R + r0 + tx] = __float2bfloat16(t[tx][cr]);
  }
}

// ------------- bf16 transpose, 64x64 tiles, vectorized both sides, dual-input -------------
__global__ __launch_bounds__(256) void transpose_bf16(const short* __restrict__ in,
                                                      short* __restrict__ out,
                                                      const short* __restrict__ in2,
                                                      short* __restrict__ out2,
                                                      int R, int C) {
  __shared__ short t[64][72];
  const int tilesC = C >> 6;
  const int tilesPer = (R >> 6) * tilesC;
  int bid = blockIdx.x;
  const short* src = in; short* dst = out;
  if (bid >= tilesPer) { bid -= tilesPer; src = in2; dst = out2; }
  const int r0 = (bid / tilesC) << 6, c0 = (bid % tilesC) << 6;
  const int tr = threadIdx.x >> 3, tc8 = (threadIdx.x & 7) << 3;
  #pragma unroll
  for (int p = 0; p < 2; ++p) {
    int r = tr + p * 32;
    int sc = tc8 ^ (((r >> 3) & 7) << 3);
    *(bf16x8*)&t[r][sc] = *(const bf16x8*)&src[(size_t)(r0 + r) * C + c0 + tc8];
  }
  __syncthreads();
  #pragma unroll
  for (int p = 0; p < 2; ++p) {
    int oc = tr + p * 32;
    bf16x8 v;
    #pragma unroll
    for (int e = 0; e < 8; ++e) {
      int a = tc8 + e;
      v[e] = t[a][oc ^ (((a >> 3) & 7) << 3)];
    }
    *(bf16x8*)&dst[(size_t)(c0 + oc) * R + r0 + tc8] = v;
  }
}

// ---------------- pack 6 bias vectors ----------------
__global__ __launch_bounds__(256) void pack_bias(const float* b0, const float* b1,
                                                 const float* b2, const float* b3,
                                                 const float* b4, const float* b5,
                                                 float* __restrict__ out) {
  int i = blockIdx.x * 256 + threadIdx.x;
  if (i < 6 * DIM) {
    int s = i >> 10, o = i & 1023;
    const float* p = (s == 0) ? b0 : (s == 1) ? b1 : (s == 2) ? b2 : (s == 3) ? b3 : (s == 4) ? b4 : b5;
    out[i] = p[o];
  }
}

// ============ 128x128 NT GEMM, BK=32, triple-buffered, 3 blocks/CU ============
// C[M,N] = A[M,K] @ Bt[N,K]^T. 256 thr = 4 waves (2x2), wave tile 64x64.
// LDS: A 3x8KB + B 3x8KB = 48 KB -> 3 blocks/CU. Both-sides chunk swizzle:
// phys chunk p of row r holds logical chunk p ^ ((r>>1)&3).
// PHASE STAGGER: resident-layer ph = (blockIdx.x>>8)%3 sleeps ph*stag*256 cyc
// at entry so the 3 co-resident blocks' MFMA/LDS/store phases interleave
// instead of colliding (round-6 MfmaUtil 31% = in-phase signature).
// EPI: 2 = sigmoid->f32 | 3 = f32 | 4 = sigmoid->f32+bf16 | 5 = fused QKV proj
template<int EPI, bool DUAL>
__global__ __launch_bounds__(256, 3) void gemm128(
    const bf16* __restrict__ A,  const bf16* __restrict__ Bt,
    const bf16* __restrict__ A2, const bf16* __restrict__ Bt2,
    int M, int N, int K, int TM, int perDir, int stag,
    const float* __restrict__ bias, const float* __restrict__ bias2, float scale,
    float* __restrict__ Cf, float* __restrict__ Cf2,
    bf16* __restrict__ Cb, bf16* __restrict__ Cb2,
    bf16* __restrict__ Cq, bf16* __restrict__ Ck, bf16* __restrict__ Cv,
    bf16* __restrict__ Cq2, bf16* __restrict__ Ck2, bf16* __restrict__ Cv2)
{
  __shared__ __align__(16) char smem[49152];
  bf16* sA = (bf16*)smem;               // 3 slots x 4096 elems (128x32)
  bf16* sB = (bf16*)(smem + 24576);     // 3 slots x 4096 elems
  float* Lf = (float*)smem;             // epilogue: 64 x 132 f32 (~34 KB)

  // ---- phase stagger (before any memory work) ----
  {
    const int ph = (blockIdx.x >> 8) % 3;
    for (int i = 0; i < ph * stag; ++i) __builtin_amdgcn_s_sleep(4);
  }

  const int t    = threadIdx.x;
  const int lane = t & 63, wid = t >> 6;
  const int wr = wid >> 1, wc = wid & 1;
  const int lr = lane & 15, kg = lane >> 4;

  // XCD-aware bijective swizzle (all grids are multiples of 8)
  const int nwg = gridDim.x;
  int bid = blockIdx.x;
  { const int q = nwg >> 3; bid = (bid & 7) * q + (bid >> 3); }

  const bf16* Au = A; const bf16* BtU = Bt;
  float* CfU = Cf; bf16* CbU = Cb;
  if (DUAL && bid >= perDir) { bid -= perDir; Au = A2; BtU = Bt2; CfU = Cf2; CbU = Cb2; }

  // stripe mapping: 8 consecutive bids share one A-panel (bm), sweep 8 bn
  const int gw = TM << 3;
  const int s  = bid / gw, w = bid % gw;
  const int bm = (w >> 3) << 7;
  const int bn = ((s << 3) + (w & 7)) << 7;

  // proj: dual-by-row select
  const float* biasU = bias;
  bf16 *CqU = Cq, *CkU = Ck, *CvU = Cv;
  int bmL = bm;
  if (EPI == 5 && bm >= (M >> 1)) {
    BtU = Bt2; biasU = bias2; CqU = Cq2; CkU = Ck2; CvU = Cv2; bmL = bm - (M >> 1);
  }

  // staging: thread t writes LDS phys chunk (t&3) of row (t>>2); global source
  // column pre-swizzled so phys chunk p of row r = logical chunk p^((r>>1)&3).
  const int srow = t >> 2;
  const int scol = ((t & 3) ^ ((t >> 3) & 3)) * 8;
  const size_t gA = (size_t)(bm + srow) * K + scol;
  const size_t gB = (size_t)(bn + srow) * K + scol;

#define STAGE(slot, isB, R0, tt_) \
  __builtin_amdgcn_global_load_lds( \
    (const __attribute__((address_space(1))) unsigned int*)(((isB) ? BtU + gB : Au + gA) + (size_t)(R0) * K + (size_t)(tt_) * 32), \
    (__attribute__((address_space(3))) unsigned int*)(((isB) ? sB : sA) + (slot) * 4096 + (R0) * 32 + t * 8), \
    16, 0, 0)

  // fragment reads: phys chunk = kg ^ ((lr>>1)&3)
  const int swz  = (kg ^ ((lr >> 1) & 3)) * 8;
  const int aoff = (wr * 64 + lr) * 32 + swz;
  const int boff = (wc * 64 + lr) * 32 + swz;

  f32x4 acc[4][4] = {};
  const int NT = K >> 5;

  // prologue: tiles 0,1 -> slots 0,1; wait tile0
  STAGE(0, 0, 0, 0); STAGE(0, 0, 64, 0); STAGE(0, 1, 0, 0); STAGE(0, 1, 64, 0);
  STAGE(1, 0, 0, 1); STAGE(1, 0, 64, 1); STAGE(1, 1, 0, 1); STAGE(1, 1, 64, 1);
  asm volatile("s_waitcnt vmcnt(4)" ::: "memory");
  __builtin_amdgcn_sched_barrier(0);
  __builtin_amdgcn_s_barrier();

  int cur = 0, stg = 2;
  for (int tt = 0; tt < NT; ++tt) {
    bf16x8 a[4], b[4];
    const bf16* pa = sA + cur * 4096 + aoff;
    const bf16* pb = sB + cur * 4096 + boff;
    #pragma unroll
    for (int i = 0; i < 4; ++i) a[i] = *(const bf16x8*)(pa + i * 512);
    #pragma unroll
    for (int i = 0; i < 4; ++i) b[i] = *(const bf16x8*)(pb + i * 512);
    if (tt + 2 < NT) {
      STAGE(stg, 0, 0, tt + 2); STAGE(stg, 0, 64, tt + 2);
      STAGE(stg, 1, 0, tt + 2); STAGE(stg, 1, 64, tt + 2);
    }
    __builtin_amdgcn_s_barrier();
    asm volatile("s_waitcnt lgkmcnt(0)" ::: "memory");
    __builtin_amdgcn_sched_barrier(0);
    __builtin_amdgcn_s_setprio(1);
    #pragma unroll
    for (int mi = 0; mi < 4; ++mi)
      #pragma unroll
      for (int n = 0; n < 4; ++n)
        acc[mi][n] = __builtin_amdgcn_mfma_f32_16x16x32_bf16(a[mi], b[n], acc[mi][n], 0, 0, 0);
    __builtin_amdgcn_s_setprio(0);
    if (tt + 2 < NT) { asm volatile("s_waitcnt vmcnt(4)" ::: "memory"); }
    else             { asm volatile("s_waitcnt vmcnt(0)" ::: "memory"); }
    __builtin_amdgcn_sched_barrier(0);
    __builtin_amdgcn_s_barrier();
    cur = (cur == 2) ? 0 : cur + 1;
    stg = (stg == 2) ? 0 : stg + 1;
  }
#undef STAGE

  // ======== LDS-transposed epilogue (64-row chunks, stride 132), coalesced ========
  float bv[4];
  if (EPI == 5) {
    #pragma unroll
    for (int n = 0; n < 4; ++n) bv[n] = biasU[bn + wc * 64 + n * 16 + lr];
  }

  #pragma unroll
  for (int h = 0; h < 2; ++h) {
    if (wr == h) {
      #pragma unroll
      for (int mi = 0; mi < 4; ++mi)
        #pragma unroll
        for (int n = 0; n < 4; ++n)
          #pragma unroll
          for (int e = 0; e < 4; ++e) {
            const int lrow = mi * 16 + kg * 4 + e;          // 0..63
            const int lcol = wc * 64 + n * 16 + lr;         // 0..127
            float v = acc[mi][n][e];
            if (EPI == 2 || EPI == 4) v = 1.0f / (1.0f + __expf(-v * scale));
            if (EPI == 5) v += bv[n];
            Lf[lrow * 132 + lcol] = v;
          }
    }
    __syncthreads();
    #pragma unroll
    for (int rr = 0; rr < 8; ++rr) {
      const int lrow = wid * 16 + rr * 2 + (lane >> 5);
      const int col  = (lane & 31) * 4;
      const f32x4 v = *(const f32x4*)&Lf[lrow * 132 + col];
      const int gr = bm + h * 64 + lrow;
      if (EPI == 2 || EPI == 4) {
        __builtin_nontemporal_store(v, (f32x4*)&CfU[(size_t)gr * N + bn + col]);
        if (EPI == 4) {
          ushort4 p; p.x = f2b(v[0]); p.y = f2b(v[1]); p.z = f2b(v[2]); p.w = f2b(v[3]);
          *(ushort4*)&CbU[(size_t)gr * N + bn + col] = p;
        }
      } else if (EPI == 3) {
        __builtin_nontemporal_store(v, (f32x4*)&CfU[(size_t)gr * N + bn + col]);
      } else if (EPI == 5) {
        const int seg = bn >> 10;
        const int cl  = (bn & 1023) + col;
        const int r   = bmL + h * 64 + lrow;
        bf16* sel = (seg == 0) ? CqU : (seg == 1) ? CkU : CvU;
        ushort4 p; p.x = f2b(v[0]); p.y = f2b(v[1]); p.z = f2b(v[2]); p.w = f2b(v[3]);
        *(ushort4*)&sel[(size_t)r * DIM + cl] = p;
      }
    }
    __syncthreads();
  }
}

// ================= legacy 128x128 GEMM (low-ws fallback only) =================
template<int EPI, bool A_F32>
__global__ __launch_bounds__(256) void gemm_nt(
    const void* __restrict__ Ap, const bf16* __restrict__ Bt,
    int M, int N, int K,
    float scale, float* __restrict__ Cf)
{
  __shared__ bf16 As[128 * 32];
  __shared__ bf16 Bs[128 * 32];
  const int tid  = threadIdx.x;
  const int lane = tid & 63, wid = tid >> 6;
  const int wrr = wid >> 1, wcc = wid & 1;
  const int tilesN = N >> 7;
  const int nwg = gridDim.x;
  int bid = blockIdx.x;
  if ((nwg & 7) == 0) { const int q = nwg >> 3; bid = (bid & 7) * q + (bid >> 3); }
  const int bm = (bid / tilesN) * 128, bn = (bid % tilesN) * 128;
  f32x4 acc[4][4] = {};
  const bf16*  Ab16 = (const bf16*)Ap;
  const float* Af32 = (const float*)Ap;
  const int srow = tid >> 2, sc8 = (tid & 3) * 8;
  const int frow = tid >> 3, fc4 = (tid & 7) * 4;

  for (int k0 = 0; k0 < K; k0 += 32) {
    if (A_F32) {
      #pragma unroll
      for (int is = 0; is < 4; ++is) {
        int row = is * 32 + frow;
        const float4 v = *(const float4*)(Af32 + (size_t)(bm + row) * K + k0 + fc4);
        ushort4 p; p.x = f2b(v.x); p.y = f2b(v.y); p.z = f2b(v.z); p.w = f2b(v.w);
        *(ushort4*)(&As[row * 32 + fc4]) = p;
      }
    } else {
      #pragma unroll
      for (int is = 0; is < 2; ++is) {
        int row = is * 64 + srow;
        const bf16* g = Ab16 + (size_t)(bm + row) * K + k0 + sc8;
        __builtin_amdgcn_global_load_lds(
            (const __attribute__((address_space(1))) unsigned int*)g,
            (__attribute__((address_space(3))) unsigned int*)(&As[row * 32 + sc8]), 16, 0, 0);
      }
    }
    #pragma unroll
    for (int is = 0; is < 2; ++is) {
      int row = is * 64 + srow;
      const bf16* g = Bt + (size_t)(bn + row) * K + k0 + sc8;
      __builtin_amdgcn_global_load_lds(
          (const __attribute__((address_space(1))) unsigned int*)g,
          (__attribute__((address_space(3))) unsigned int*)(&Bs[row * 32 + sc8]), 16, 0, 0);
    }
    __syncthreads();
    const int lrr = lane & 15, kgg = lane >> 4;
    bf16x8 af[4], bfv[4];
    #pragma unroll
    for (int i = 0; i < 4; ++i)
      af[i] = *(const bf16x8*)(&As[(wrr * 64 + i * 16 + lrr) * 32 + kgg * 8]);
    #pragma unroll
    for (int j = 0; j < 4; ++j)
      bfv[j] = *(const bf16x8*)(&Bs[(wcc * 64 + j * 16 + lrr) * 32 + kgg * 8]);
    #pragma unroll
    for (int i = 0; i < 4; ++i)
      #pragma unroll
      for (int j = 0; j < 4; ++j)
        acc[i][j] = __builtin_amdgcn_mfma_f32_16x16x32_bf16(af[i], bfv[j], acc[i][j], 0, 0, 0);
    __syncthreads();
  }
  const int r0 = bm + wrr * 64 + (lane >> 4) * 4;
  const int c0 = bn + wcc * 64 + (lane & 15);
  if (EPI == 2) {
    #pragma unroll
    for (int i = 0; i < 4; ++i)
      #pragma unroll
      for (int j = 0; j < 4; ++j)
        #pragma unroll
        for (int e = 0; e < 4; ++e) {
          float pr = 1.0f / (1.0f + __expf(-acc[i][j][e] * scale));
          Cf[(size_t)(r0 + i * 16 + e) * N + c0 + j * 16] = pr;
        }
  } else {
    #pragma unroll
    for (int i = 0; i < 4; ++i)
      #pragma unroll
      for (int j = 0; j < 4; ++j)
        #pragma unroll
        for (int e = 0; e < 4; ++e)
          Cf[(size_t)(r0 + i * 16 + e) * N + c0 + j * 16] = acc[i][j][e];
  }
}

extern "C" void kernel_launch(void* const* d_in, const int* in_sizes, int n_in,
                              void* d_out, int out_size, void* d_ws, size_t ws_size,
                              hipStream_t stream) {
  const float* x1 = (const float*)d_in[0];
  const float* x2 = (const float*)d_in[1];
  const float* W[6] = { (const float*)d_in[2],  (const float*)d_in[4],  (const float*)d_in[6],
                        (const float*)d_in[8],  (const float*)d_in[10], (const float*)d_in[12] };
  const float* B[6] = { (const float*)d_in[3],  (const float*)d_in[5],  (const float*)d_in[7],
                        (const float*)d_in[9],  (const float*)d_in[11], (const float*)d_in[13] };

  const size_t MD = (size_t)NTOK * DIM;
  const size_t DD = (size_t)DIM * DIM;
  const size_t NN = (size_t)NTOK * NTOK;

  bf16* ws   = (bf16*)d_ws;
  bf16* x1b  = ws;                         // contiguous with x2b -> proj A (16384 rows)
  bf16* x2b  = x1b + MD;
  bf16* wt1  = x2b + MD;
  bf16* wt2  = wt1 + 3 * DD;
  float* bstack = (float*)(wt2 + 3 * DD);  // 6144 f32 in 16384-bf16 slot
  bf16* q1   = wt2 + 3 * DD + 16384;
  bf16* k1   = q1 + MD;
  bf16* q2   = k1 + MD;
  bf16* k2   = q2 + MD;
  bf16* v1r  = k2 + MD;
  bf16* v2r  = v1r + MD;
  bf16* v1T  = v2r + MD;
  bf16* v2T  = v1T + MD;
  bf16* probsb = v2T + MD;                 // 2 x 64M bf16

  const size_t topBytes = ((size_t)(10 * MD + 6 * DD + 16384) + 2 * NN) * 2;
  const bool top = (ws_size >= topBytes);  // ~440 MB; measured ws ≈ 2.4 GB

  float* out    = (float*)d_out;
  float* ctx2   = out;
  float* probs2 = ctx2 + MD;
  float* ctx1   = probs2 + NN;
  float* probs1 = ctx1 + MD;

  const float scale = 1.0f / 32.0f;

  {
    int n4 = (int)(MD / 4);
    int blks = (n4 + 255) / 256;
    cast_f32_bf16<<<blks, 256, 0, stream>>>(x1, x1b, n4);
    cast_f32_bf16<<<blks, 256, 0, stream>>>(x2, x2b, n4);
  }
  {
    int blks = (DIM / 32) * (DIM / 32);
    transpose_cast32<<<blks, 256, 0, stream>>>(W[0], wt1 + 0 * DD, DIM, DIM);
    transpose_cast32<<<blks, 256, 0, stream>>>(W[1], wt1 + 1 * DD, DIM, DIM);
    transpose_cast32<<<blks, 256, 0, stream>>>(W[2], wt1 + 2 * DD, DIM, DIM);
    transpose_cast32<<<blks, 256, 0, stream>>>(W[3], wt2 + 0 * DD, DIM, DIM);
    transpose_cast32<<<blks, 256, 0, stream>>>(W[4], wt2 + 1 * DD, DIM, DIM);
    transpose_cast32<<<blks, 256, 0, stream>>>(W[5], wt2 + 2 * DD, DIM, DIM);
  }
  pack_bias<<<24, 256, 0, stream>>>(B[0], B[1], B[2], B[3], B[4], B[5], bstack);

  // fused QKV projection: A = [x1b;x2b] (16384 x 1024), N = 3072. grid 3072.
  gemm128<5, false><<<128 * 24, 256, 0, stream>>>(
      x1b, wt1, nullptr, wt2, 2 * NTOK, 3 * DIM, DIM, 128, 3072, 8,
      bstack, bstack + 3 * DIM, 0.f,
      nullptr, nullptr, nullptr, nullptr,
      q1, k1, v1r, q2, k2, v2r);

  // v transpose: [8192,1024] -> [1024,8192], both inputs
  transpose_bf16<<<2 * (NTOK / 64) * (DIM / 64), 256, 0, stream>>>(
      (const short*)v1r, (short*)v1T, (const short*)v2r, (short*)v2T, NTOK, DIM);

  const int perQK = (NTOK / 128) * (NTOK / 128);  // 4096
  const int perPV = (NTOK / 128) * (DIM / 128);   // 512

  if (top) {
    // fused dual QK: dir0 probs2 = sig(s*q1@k2^T), dir1 probs1 = sig(s*q2@k1^T)
    gemm128<4, true><<<2 * perQK, 256, 0, stream>>>(
        q1, k2, q2, k1, NTOK, NTOK, DIM, 64, perQK, 16,
        nullptr, nullptr, scale,
        probs2, probs1, probsb, probsb + NN,
        nullptr, nullptr, nullptr, nullptr, nullptr, nullptr);
    // fused dual PV: ctx2 = probsb@v2, ctx1 = probsb'@v1 (K = 8192)
    gemm128<3, true><<<2 * perPV, 256, 0, stream>>>(
        probsb, v2T, probsb + NN, v1T, NTOK, DIM, NTOK, 64, perPV, 32,
        nullptr, nullptr, 0.f,
        ctx2, ctx1, nullptr, nullptr,
        nullptr, nullptr, nullptr, nullptr, nullptr, nullptr);
  } else {
    // fallback: f32 probs only; PV re-reads f32 probs from d_out with convert-on-stage
    gemm128<2, false><<<perQK, 256, 0, stream>>>(
        q1, k2, nullptr, nullptr, NTOK, NTOK, DIM, 64, perQK, 16,
        nullptr, nullptr, scale,
        probs2, nullptr, nullptr, nullptr,
        nullptr, nullptr, nullptr, nullptr, nullptr, nullptr);
    gemm_nt<3, true><<<(NTOK / 128) * (DIM / 128), 256, 0, stream>>>(
        probs2, v2T, NTOK, DIM, NTOK, 0.f, ctx2);
    gemm128<2, false><<<perQK, 256, 0, stream>>>(
        q2, k1, nullptr, nullptr, NTOK, NTOK, DIM, 64, perQK, 16,
        nullptr, nullptr, scale,
        probs1, nullptr, nullptr, nullptr,
        nullptr, nullptr, nullptr, nullptr, nullptr, nullptr);
    gemm_nt<3, true><<<(NTOK / 128) * (DIM / 128), 256, 0, stream>>>(
        probs1, v1T, NTOK, DIM, NTOK, 0.f, ctx1);
  }
}

// Round 9
// 772.445 us; speedup vs baseline: 1.5124x; 1.1568x over previous
//
#include <hip/hip_runtime.h>
#include <hip/hip_bf16.h>

#define DIM   1024
#define NTOK  8192

using bf16 = __hip_bfloat16;
typedef __attribute__((ext_vector_type(8))) short bf16x8;
typedef __attribute__((ext_vector_type(4))) float f32x4;

__device__ __forceinline__ unsigned short f2b(float x) {
  union { __hip_bfloat16 h; unsigned short u; } cv;
  cv.h = __float2bfloat16(x);
  return cv.u;
}

// ---------------- cast f32 -> bf16 ----------------
__global__ __launch_bounds__(256) void cast_f32_bf16(const float* __restrict__ in,
                                                     bf16* __restrict__ out, int n4) {
  int i = blockIdx.x * 256 + threadIdx.x;
  if (i < n4) {
    const float4 v = ((const float4*)in)[i];
    ushort4 p;
    p.x = f2b(v.x); p.y = f2b(v.y); p.z = f2b(v.z); p.w = f2b(v.w);
    ((ushort4*)out)[i] = p;
  }
}

// ------------- tiled transpose + cast: in[R][C] f32 -> out[C][R] bf16 -------------
__global__ __launch_bounds__(256) void transpose_cast32(const float* __restrict__ in,
                                                        bf16* __restrict__ out, int R, int C) {
  __shared__ float t[32][33];
  const int tilesC = C / 32;
  const int c0 = (blockIdx.x % tilesC) * 32;
  const int r0 = (blockIdx.x / tilesC) * 32;
  const int tx = threadIdx.x & 31, ty = threadIdx.x >> 5;
  #pragma unroll
  for (int i = 0; i < 4; ++i) {
    int r = ty + i * 8;
    t[r][tx] = in[(size_t)(r0 + r) * C + c0 + tx];
  }
  __syncthreads();
  #pragma unroll
  for (int i = 0; i < 4; ++i) {
    int cr = ty + i * 8;
    out[(size_t)(c0 + cr) * R + r0 + tx] = __float2bfloat16(t[tx][cr]);
  }
}

// ------------- bf16 transpose, 64x64 tiles, vectorized both sides, dual-input -------------
__global__ __launch_bounds__(256) void transpose_bf16(const short* __restrict__ in,
                                                      short* __restrict__ out,
                                                      const short* __restrict__ in2,
                                                      short* __restrict__ out2,
                                                      int R, int C) {
  __shared__ short t[64][72];
  const int tilesC = C >> 6;
  const int tilesPer = (R >> 6) * tilesC;
  int bid = blockIdx.x;
  const short* src = in; short* dst = out;
  if (bid >= tilesPer) { bid -= tilesPer; src = in2; dst = out2; }
  const int r0 = (bid / tilesC) << 6, c0 = (bid % tilesC) << 6;
  const int tr = threadIdx.x >> 3, tc8 = (threadIdx.x & 7) << 3;
  #pragma unroll
  for (int p = 0; p < 2; ++p) {
    int r = tr + p * 32;
    int sc = tc8 ^ (((r >> 3) & 7) << 3);
    *(bf16x8*)&t[r][sc] = *(const bf16x8*)&src[(size_t)(r0 + r) * C + c0 + tc8];
  }
  __syncthreads();
  #pragma unroll
  for (int p = 0; p < 2; ++p) {
    int oc = tr + p * 32;
    bf16x8 v;
    #pragma unroll
    for (int e = 0; e < 8; ++e) {
      int a = tc8 + e;
      v[e] = t[a][oc ^ (((a >> 3) & 7) << 3)];
    }
    *(bf16x8*)&dst[(size_t)(c0 + oc) * R + r0 + tc8] = v;
  }
}

// ---------------- pack 6 bias vectors ----------------
__global__ __launch_bounds__(256) void pack_bias(const float* b0, const float* b1,
                                                 const float* b2, const float* b3,
                                                 const float* b4, const float* b5,
                                                 float* __restrict__ out) {
  int i = blockIdx.x * 256 + threadIdx.x;
  if (i < 6 * DIM) {
    int s = i >> 10, o = i & 1023;
    const float* p = (s == 0) ? b0 : (s == 1) ? b1 : (s == 2) ? b2 : (s == 3) ? b3 : (s == 4) ? b4 : b5;
    out[i] = p[o];
  }
}

// ================= 256x256 8-phase NT GEMM (T1+T2+T3+T4+T5) =================
// C[M,N] = A[M,K] @ Bt[N,K]^T. BK=64, 512 thr = 8 waves (2M x 4N), wave tile 128x64.
// __launch_bounds__(512, 1): 256-VGPR cap -> acc[8][4] stays in registers
// (round-4's (512,2) capped at 128 VGPR and spilled the accumulator: VGPR_Count=108).
// LDS 2 x 64KB double-buffer, XOR-swizzled (col16 ^= row&7) via pre-swizzled
// global source + swizzled ds_read (rule #21). Counted vmcnt(4), never 0 in loop.
// EPI: 2 = sigmoid->f32 | 3 = f32 | 4 = sigmoid->f32+bf16 | 5 = fused QKV proj
template<int EPI, bool DUAL>
__global__ __launch_bounds__(512, 1) void gemm256(
    const bf16* __restrict__ A,  const bf16* __restrict__ Bt,
    const bf16* __restrict__ A2, const bf16* __restrict__ Bt2,
    int M, int N, int K, int tilesN, int perDir,
    const float* __restrict__ bias, const float* __restrict__ bias2, float scale,
    float* __restrict__ Cf, float* __restrict__ Cf2,
    bf16* __restrict__ Cb, bf16* __restrict__ Cb2,
    bf16* __restrict__ Cq, bf16* __restrict__ Ck, bf16* __restrict__ Cv,
    bf16* __restrict__ Cq2, bf16* __restrict__ Ck2, bf16* __restrict__ Cv2)
{
  __shared__ bf16 lds[2][2 * 16384];
  const int t    = threadIdx.x;
  const int lane = t & 63, wid = t >> 6;
  const int wr = wid >> 2, wc = wid & 3;
  const int lr = lane & 15, kg = lane >> 4;

  // XCD-aware bijective swizzle (all grids are multiples of 8)
  const int nwg = gridDim.x;
  int bid = blockIdx.x;
  { const int q = nwg >> 3; bid = (bid & 7) * q + (bid >> 3); }

  const bf16* Au = A; const bf16* BtU = Bt;
  float* CfU = Cf; bf16* CbU = Cb;
  if (DUAL && bid >= perDir) { bid -= perDir; Au = A2; BtU = Bt2; CfU = Cf2; CbU = Cb2; }

  const int bm = (bid / tilesN) << 8;
  const int bn = (bid % tilesN) << 8;

  // proj: dual-by-row select
  const float* biasU = bias;
  bf16 *CqU = Cq, *CkU = Ck, *CvU = Cv;
  int bmL = bm;
  if (EPI == 5 && bm >= (M >> 1)) {
    BtU = Bt2; biasU = bias2; CqU = Cq2; CkU = Ck2; CvU = Cv2; bmL = bm - (M >> 1);
  }

  // staging: thread t covers one 16B chunk of each 64-row region; source col pre-swizzled
  const int srow = t >> 3;
  const int scol = ((t & 7) ^ (srow & 7)) * 8;
  const size_t bA = (size_t)(bm + srow) * K + scol;
  const size_t bB = (size_t)(bn + srow) * K + scol;

#define STAGE(buf, isB, R0, tt_) do {                                                   \
    const bf16* g_ = ((isB) ? BtU + bB : Au + bA) + (size_t)(R0) * K + (size_t)(tt_) * 64; \
    __builtin_amdgcn_global_load_lds(                                                   \
        (const __attribute__((address_space(1))) unsigned int*)g_,                      \
        (__attribute__((address_space(3))) unsigned int*)(&lds[buf][((isB) ? 16384 : 0) + (R0) * 64 + t * 8]), \
        16, 0, 0);                                                                      \
  } while (0)

  // fragment read offsets (swizzled): col16 = (kk*4+kg) ^ (lr&7)
  const int fcol0 = ((kg)     ^ (lr & 7)) * 8;
  const int fcol1 = ((4 + kg) ^ (lr & 7)) * 8;
  const int arow = (wr * 128 + lr) * 64;
  const int brow = (wc * 64 + lr) * 64;

  f32x4 acc[8][4] = {};
  const int NT = K >> 6;

  // ---- prologue: tile0 full -> buf0; tile1 half -> buf1 ----
  STAGE(0, false, 0, 0);   STAGE(0, false, 128, 0);
  STAGE(0, false, 64, 0);  STAGE(0, false, 192, 0);
  STAGE(0, true, 0, 0);    STAGE(0, true, 64, 0);
  STAGE(0, true, 128, 0);  STAGE(0, true, 192, 0);
  if (NT > 1) {
    STAGE(1, false, 0, 1); STAGE(1, false, 128, 1);
    STAGE(1, true, 0, 1);  STAGE(1, true, 64, 1);
    asm volatile("s_waitcnt vmcnt(4)" ::: "memory");
  } else {
    asm volatile("s_waitcnt vmcnt(0)" ::: "memory");
  }
  __builtin_amdgcn_sched_barrier(0);
  __builtin_amdgcn_s_barrier();

  for (int tt = 0; tt < NT; ++tt) {
    const int cur = tt & 1;
    const bf16* bufA = &lds[cur][0];
    const bf16* bufB = &lds[cur][16384];
    bf16x8 b0[4], b1[4];

    { // P1: mh=0, kk=0
      bf16x8 a[4];
      #pragma unroll
      for (int n = 0; n < 4; ++n) b0[n] = *(const bf16x8*)(bufB + brow + n * 1024 + fcol0);
      #pragma unroll
      for (int mi = 0; mi < 4; ++mi) a[mi] = *(const bf16x8*)(bufA + arow + mi * 1024 + fcol0);
      if (tt + 1 < NT) { STAGE(cur ^ 1, true, 128, tt + 1); STAGE(cur ^ 1, true, 192, tt + 1); }
      __builtin_amdgcn_s_barrier();
      asm volatile("s_waitcnt lgkmcnt(0)" ::: "memory");
      __builtin_amdgcn_sched_barrier(0);
      __builtin_amdgcn_s_setprio(1);
      #pragma unroll
      for (int mi = 0; mi < 4; ++mi)
        #pragma unroll
        for (int n = 0; n < 4; ++n)
          acc[mi][n] = __builtin_amdgcn_mfma_f32_16x16x32_bf16(a[mi], b0[n], acc[mi][n], 0, 0, 0);
      __builtin_amdgcn_s_setprio(0);
      __builtin_amdgcn_s_barrier();
    }
    { // P2: mh=0, kk=1
      bf16x8 a[4];
      #pragma unroll
      for (int n = 0; n < 4; ++n) b1[n] = *(const bf16x8*)(bufB + brow + n * 1024 + fcol1);
      #pragma unroll
      for (int mi = 0; mi < 4; ++mi) a[mi] = *(const bf16x8*)(bufA + arow + mi * 1024 + fcol1);
      if (tt + 1 < NT) { STAGE(cur ^ 1, false, 64, tt + 1); STAGE(cur ^ 1, false, 192, tt + 1); }
      __builtin_amdgcn_s_barrier();
      asm volatile("s_waitcnt lgkmcnt(0)" ::: "memory");
      __builtin_amdgcn_sched_barrier(0);
      __builtin_amdgcn_s_setprio(1);
      #pragma unroll
      for (int mi = 0; mi < 4; ++mi)
        #pragma unroll
        for (int n = 0; n < 4; ++n)
          acc[mi][n] = __builtin_amdgcn_mfma_f32_16x16x32_bf16(a[mi], b1[n], acc[mi][n], 0, 0, 0);
      __builtin_amdgcn_s_setprio(0);
      __builtin_amdgcn_s_barrier();
    }
    { // P3: mh=1, kk=0
      bf16x8 a[4];
      #pragma unroll
      for (int mi = 0; mi < 4; ++mi) a[mi] = *(const bf16x8*)(bufA + arow + 4096 + mi * 1024 + fcol0);
      if (tt + 2 < NT) { STAGE(cur, false, 0, tt + 2); STAGE(cur, false, 128, tt + 2); }
      __builtin_amdgcn_s_barrier();
      asm volatile("s_waitcnt lgkmcnt(0)" ::: "memory");
      __builtin_amdgcn_sched_barrier(0);
      __builtin_amdgcn_s_setprio(1);
      #pragma unroll
      for (int mi = 0; mi < 4; ++mi)
        #pragma unroll
        for (int n = 0; n < 4; ++n)
          acc[4 + mi][n] = __builtin_amdgcn_mfma_f32_16x16x32_bf16(a[mi], b0[n], acc[4 + mi][n], 0, 0, 0);
      __builtin_amdgcn_s_setprio(0);
      __builtin_amdgcn_s_barrier();
    }
    { // P4: mh=1, kk=1
      bf16x8 a[4];
      #pragma unroll
      for (int mi = 0; mi < 4; ++mi) a[mi] = *(const bf16x8*)(bufA + arow + 4096 + mi * 1024 + fcol1);
      if (tt + 2 < NT) { STAGE(cur, true, 0, tt + 2); STAGE(cur, true, 64, tt + 2); }
      __builtin_amdgcn_s_barrier();
      asm volatile("s_waitcnt lgkmcnt(0)" ::: "memory");
      __builtin_amdgcn_sched_barrier(0);
      __builtin_amdgcn_s_setprio(1);
      #pragma unroll
      for (int mi = 0; mi < 4; ++mi)
        #pragma unroll
        for (int n = 0; n < 4; ++n)
          acc[4 + mi][n] = __builtin_amdgcn_mfma_f32_16x16x32_bf16(a[mi], b1[n], acc[4 + mi][n], 0, 0, 0);
      __builtin_amdgcn_s_setprio(0);
      if (tt + 2 < NT) { asm volatile("s_waitcnt vmcnt(4)" ::: "memory"); }
      else             { asm volatile("s_waitcnt vmcnt(0)" ::: "memory"); }
      __builtin_amdgcn_sched_barrier(0);
      __builtin_amdgcn_s_barrier();
    }
  }
#undef STAGE

  // ======== LDS-transposed epilogue: coalesced stores ========
  // acc[m][n][e]: global row = bm + wr*128 + kg*4 + m*16 + e, col = bn + wc*64 + n*16 + lr.
  float* Lf = (float*)&lds[0][0];   // 32768 f32 = 128 KiB

  float bN[4];
  if (EPI == 5) {
    #pragma unroll
    for (int n = 0; n < 4; ++n) bN[n] = biasU[bn + wc * 64 + n * 16 + lr];
  }

  #pragma unroll
  for (int h = 0; h < 2; ++h) {
    if (wr == h) {
      #pragma unroll
      for (int m = 0; m < 8; ++m)
        #pragma unroll
        for (int n = 0; n < 4; ++n)
          #pragma unroll
          for (int e = 0; e < 4; ++e) {
            const int lrow = kg * 4 + m * 16 + e;          // 0..127
            const int lcol = wc * 64 + n * 16 + lr;        // 0..255
            float v = acc[m][n][e];
            if (EPI == 2 || EPI == 4) v = 1.0f / (1.0f + __expf(-v * scale));
            if (EPI == 5) v += bN[n];
            Lf[lrow * 256 + (lcol ^ (((lrow >> 2) & 3) << 4))] = v;
          }
    }
    __syncthreads();
    // wave wid handles rows [wid*16, wid*16+16)
    #pragma unroll
    for (int rr = 0; rr < 16; ++rr) {
      const int lrow = wid * 16 + rr;
      const int cb   = lane * 4;                            // 0..252
      const int cbs  = cb ^ (((lrow >> 2) & 3) << 4);
      const f32x4 v  = *(const f32x4*)&Lf[lrow * 256 + cbs];
      const int gr   = bm + h * 128 + lrow;
      const int gc   = bn + cb;
      if (EPI == 2 || EPI == 4) {
        __builtin_nontemporal_store(v, (f32x4*)&CfU[(size_t)gr * N + gc]);
        if (EPI == 4) {
          ushort4 p; p.x = f2b(v[0]); p.y = f2b(v[1]); p.z = f2b(v[2]); p.w = f2b(v[3]);
          *(ushort4*)&CbU[(size_t)gr * N + gc] = p;
        }
      } else if (EPI == 3) {
        __builtin_nontemporal_store(v, (f32x4*)&CfU[(size_t)gr * N + gc]);
      } else if (EPI == 5) {
        const int seg = bn >> 10;              // 0=q 1=k 2=v (block-uniform; 256|1024)
        const int cl  = (bn & 1023) + cb;
        const int r   = bmL + h * 128 + lrow;
        bf16* sel = (seg == 0) ? CqU : (seg == 1) ? CkU : CvU;
        ushort4 p; p.x = f2b(v[0]); p.y = f2b(v[1]); p.z = f2b(v[2]); p.w = f2b(v[3]);
        *(ushort4*)&sel[(size_t)r * DIM + cl] = p;
      }
    }
    __syncthreads();
  }
}

// ================= legacy 128x128 GEMM (low-ws fallback only) =================
template<int EPI, bool A_F32>
__global__ __launch_bounds__(256) void gemm_nt(
    const void* __restrict__ Ap, const bf16* __restrict__ Bt,
    int M, int N, int K,
    float scale, float* __restrict__ Cf)
{
  __shared__ bf16 As[128 * 32];
  __shared__ bf16 Bs[128 * 32];
  const int tid  = threadIdx.x;
  const int lane = tid & 63, wid = tid >> 6;
  const int wrr = wid >> 1, wcc = wid & 1;
  const int tilesN = N >> 7;
  const int nwg = gridDim.x;
  int bid = blockIdx.x;
  if ((nwg & 7) == 0) { const int q = nwg >> 3; bid = (bid & 7) * q + (bid >> 3); }
  const int bm = (bid / tilesN) * 128, bn = (bid % tilesN) * 128;
  f32x4 acc[4][4] = {};
  const bf16*  Ab16 = (const bf16*)Ap;
  const float* Af32 = (const float*)Ap;
  const int srow = tid >> 2, sc8 = (tid & 3) * 8;
  const int frow = tid >> 3, fc4 = (tid & 7) * 4;

  for (int k0 = 0; k0 < K; k0 += 32) {
    if (A_F32) {
      #pragma unroll
      for (int is = 0; is < 4; ++is) {
        int row = is * 32 + frow;
        const float4 v = *(const float4*)(Af32 + (size_t)(bm + row) * K + k0 + fc4);
        ushort4 p; p.x = f2b(v.x); p.y = f2b(v.y); p.z = f2b(v.z); p.w = f2b(v.w);
        *(ushort4*)(&As[row * 32 + fc4]) = p;
      }
    } else {
      #pragma unroll
      for (int is = 0; is < 2; ++is) {
        int row = is * 64 + srow;
        const bf16* g = Ab16 + (size_t)(bm + row) * K + k0 + sc8;
        __builtin_amdgcn_global_load_lds(
            (const __attribute__((address_space(1))) unsigned int*)g,
            (__attribute__((address_space(3))) unsigned int*)(&As[row * 32 + sc8]), 16, 0, 0);
      }
    }
    #pragma unroll
    for (int is = 0; is < 2; ++is) {
      int row = is * 64 + srow;
      const bf16* g = Bt + (size_t)(bn + row) * K + k0 + sc8;
      __builtin_amdgcn_global_load_lds(
          (const __attribute__((address_space(1))) unsigned int*)g,
          (__attribute__((address_space(3))) unsigned int*)(&Bs[row * 32 + sc8]), 16, 0, 0);
    }
    __syncthreads();
    const int lrr = lane & 15, kgg = lane >> 4;
    bf16x8 af[4], bfv[4];
    #pragma unroll
    for (int i = 0; i < 4; ++i)
      af[i] = *(const bf16x8*)(&As[(wrr * 64 + i * 16 + lrr) * 32 + kgg * 8]);
    #pragma unroll
    for (int j = 0; j < 4; ++j)
      bfv[j] = *(const bf16x8*)(&Bs[(wcc * 64 + j * 16 + lrr) * 32 + kgg * 8]);
    #pragma unroll
    for (int i = 0; i < 4; ++i)
      #pragma unroll
      for (int j = 0; j < 4; ++j)
        acc[i][j] = __builtin_amdgcn_mfma_f32_16x16x32_bf16(af[i], bfv[j], acc[i][j], 0, 0, 0);
    __syncthreads();
  }
  const int r0 = bm + wrr * 64 + (lane >> 4) * 4;
  const int c0 = bn + wcc * 64 + (lane & 15);
  if (EPI == 2) {
    #pragma unroll
    for (int i = 0; i < 4; ++i)
      #pragma unroll
      for (int j = 0; j < 4; ++j)
        #pragma unroll
        for (int e = 0; e < 4; ++e) {
          float pr = 1.0f / (1.0f + __expf(-acc[i][j][e] * scale));
          Cf[(size_t)(r0 + i * 16 + e) * N + c0 + j * 16] = pr;
        }
  } else {
    #pragma unroll
    for (int i = 0; i < 4; ++i)
      #pragma unroll
      for (int j = 0; j < 4; ++j)
        #pragma unroll
        for (int e = 0; e < 4; ++e)
          Cf[(size_t)(r0 + i * 16 + e) * N + c0 + j * 16] = acc[i][j][e];
  }
}

extern "C" void kernel_launch(void* const* d_in, const int* in_sizes, int n_in,
                              void* d_out, int out_size, void* d_ws, size_t ws_size,
                              hipStream_t stream) {
  const float* x1 = (const float*)d_in[0];
  const float* x2 = (const float*)d_in[1];
  const float* W[6] = { (const float*)d_in[2],  (const float*)d_in[4],  (const float*)d_in[6],
                        (const float*)d_in[8],  (const float*)d_in[10], (const float*)d_in[12] };
  const float* B[6] = { (const float*)d_in[3],  (const float*)d_in[5],  (const float*)d_in[7],
                        (const float*)d_in[9],  (const float*)d_in[11], (const float*)d_in[13] };

  const size_t MD = (size_t)NTOK * DIM;
  const size_t DD = (size_t)DIM * DIM;
  const size_t NN = (size_t)NTOK * NTOK;

  bf16* ws   = (bf16*)d_ws;
  bf16* x1b  = ws;                         // contiguous with x2b -> proj A (16384 rows)
  bf16* x2b  = x1b + MD;
  bf16* wt1  = x2b + MD;
  bf16* wt2  = wt1 + 3 * DD;
  float* bstack = (float*)(wt2 + 3 * DD);  // 6144 f32 in 16384-bf16 slot
  bf16* q1   = wt2 + 3 * DD + 16384;
  bf16* k1   = q1 + MD;
  bf16* q2   = k1 + MD;
  bf16* k2   = q2 + MD;
  bf16* v1r  = k2 + MD;
  bf16* v2r  = v1r + MD;
  bf16* v1T  = v2r + MD;
  bf16* v2T  = v1T + MD;
  bf16* probsb = v2T + MD;                 // 2 x 64M bf16

  const size_t topBytes = ((size_t)(10 * MD + 6 * DD + 16384) + 2 * NN) * 2;
  const bool top = (ws_size >= topBytes);  // ~440 MB; measured ws ≈ 2.4 GB

  float* out    = (float*)d_out;
  float* ctx2   = out;
  float* probs2 = ctx2 + MD;
  float* ctx1   = probs2 + NN;
  float* probs1 = ctx1 + MD;

  const float scale = 1.0f / 32.0f;

  {
    int n4 = (int)(MD / 4);
    int blks = (n4 + 255) / 256;
    cast_f32_bf16<<<blks, 256, 0, stream>>>(x1, x1b, n4);
    cast_f32_bf16<<<blks, 256, 0, stream>>>(x2, x2b, n4);
  }
  {
    int blks = (DIM / 32) * (DIM / 32);
    transpose_cast32<<<blks, 256, 0, stream>>>(W[0], wt1 + 0 * DD, DIM, DIM);
    transpose_cast32<<<blks, 256, 0, stream>>>(W[1], wt1 + 1 * DD, DIM, DIM);
    transpose_cast32<<<blks, 256, 0, stream>>>(W[2], wt1 + 2 * DD, DIM, DIM);
    transpose_cast32<<<blks, 256, 0, stream>>>(W[3], wt2 + 0 * DD, DIM, DIM);
    transpose_cast32<<<blks, 256, 0, stream>>>(W[4], wt2 + 1 * DD, DIM, DIM);
    transpose_cast32<<<blks, 256, 0, stream>>>(W[5], wt2 + 2 * DD, DIM, DIM);
  }
  pack_bias<<<24, 256, 0, stream>>>(B[0], B[1], B[2], B[3], B[4], B[5], bstack);

  // fused QKV projection: A = [x1b;x2b] (16384 x 1024), N = 3072.
  // grid 64 M-tiles x 12 N-tiles = 768 blocks (3/CU).
  gemm256<5, false><<<64 * 12, 512, 0, stream>>>(
      x1b, wt1, nullptr, wt2, 2 * NTOK, 3 * DIM, DIM, 12, 768,
      bstack, bstack + 3 * DIM, 0.f,
      nullptr, nullptr, nullptr, nullptr,
      q1, k1, v1r, q2, k2, v2r);

  // v transpose: [8192,1024] -> [1024,8192], both inputs
  transpose_bf16<<<2 * (NTOK / 64) * (DIM / 64), 256, 0, stream>>>(
      (const short*)v1r, (short*)v1T, (const short*)v2r, (short*)v2T, NTOK, DIM);

  const int perQK = (NTOK / 256) * (NTOK / 256);  // 1024
  const int perPV = (NTOK / 256) * (DIM / 256);   // 128

  if (top) {
    // fused dual QK: dir0 probs2 = sig(s*q1@k2^T) -> f32+bf16; dir1 likewise. 2048 blocks.
    gemm256<4, true><<<2 * perQK, 512, 0, stream>>>(
        q1, k2, q2, k1, NTOK, NTOK, DIM, 32, perQK,
        nullptr, nullptr, scale,
        probs2, probs1, probsb, probsb + NN,
        nullptr, nullptr, nullptr, nullptr, nullptr, nullptr);
    // fused dual PV: ctx2 = probsb@v2, ctx1 = probsb'@v1. K=8192, NT=128. 256 blocks = 1/CU.
    gemm256<3, true><<<2 * perPV, 512, 0, stream>>>(
        probsb, v2T, probsb + NN, v1T, NTOK, DIM, NTOK, 4, perPV,
        nullptr, nullptr, 0.f,
        ctx2, ctx1, nullptr, nullptr,
        nullptr, nullptr, nullptr, nullptr, nullptr, nullptr);
  } else {
    // fallback: f32 probs only; PV re-reads f32 probs from d_out with convert-on-stage
    gemm256<2, false><<<perQK, 512, 0, stream>>>(
        q1, k2, nullptr, nullptr, NTOK, NTOK, DIM, 32, perQK,
        nullptr, nullptr, scale,
        probs2, nullptr, nullptr, nullptr,
        nullptr, nullptr, nullptr, nullptr, nullptr, nullptr);
    gemm_nt<3, true><<<(NTOK / 128) * (DIM / 128), 256, 0, stream>>>(
        probs2, v2T, NTOK, DIM, NTOK, 0.f, ctx2);
    gemm256<2, false><<<perQK, 512, 0, stream>>>(
        q2, k1, nullptr, nullptr, NTOK, NTOK, DIM, 32, perQK,
        nullptr, nullptr, scale,
        probs1, nullptr, nullptr, nullptr,
        nullptr, nullptr, nullptr, nullptr, nullptr, nullptr);
    gemm_nt<3, true><<<(NTOK / 128) * (DIM / 128), 256, 0, stream>>>(
        probs1, v1T, NTOK, DIM, NTOK, 0.f, ctx1);
  }
}